// Round 3
// baseline (232.782 us; speedup 1.0000x reference)
//
#include <hip/hip_runtime.h>
#include <cstdint>

#define LN_EPS 1e-12f
#define NTOK 32768
#define HDIM 768
#define DDIM 16
#define MMEM 50

// ws layout (floats)
#define WS_W1   0        // 12288: g1-folded W_down
#define WS_G    12288    // 16
#define WS_C    12304    // 16 (includes b_down)
#define WS_KEY  12320    // 800
#define WS_VAL  13120    // 800
#define WS_R    16384    // 32768*16

__global__ __launch_bounds__(256) void pre_kernel(
    const float* __restrict__ g1, const float* __restrict__ b1,
    const float* __restrict__ W_down, const float* __restrict__ b_down,
    const float* __restrict__ memory, const float* __restrict__ W_k,
    const float* __restrict__ b_k, const float* __restrict__ W_v,
    const float* __restrict__ b_v, float* __restrict__ ws)
{
    const int tid = threadIdx.x;
    // W1 = diag(g1) @ W_down
    const float4* Wd4 = (const float4*)W_down;
    float4* W14 = (float4*)(ws + WS_W1);
    for (int e = tid; e < (HDIM*DDIM)/4; e += 256) {
        const int i = e >> 2;
        float4 w = Wd4[e];
        const float s = g1[i];
        w.x *= s; w.y *= s; w.z *= s; w.w *= s;
        W14[e] = w;
    }
    // G[k] = sum_i g1[i]*Wd[i,k];  C[k] = sum_i b1[i]*Wd[i,k] + b_down[k]
    __shared__ float redG[16][17];
    __shared__ float redC[16][17];
    const int k = tid & 15, g = tid >> 4;
    float pG = 0.f, pC = 0.f;
    for (int i = g*(HDIM/16); i < (g+1)*(HDIM/16); ++i) {
        const float w = W_down[i*DDIM + k];
        pG = fmaf(g1[i], w, pG);
        pC = fmaf(b1[i], w, pC);
    }
    redG[g][k] = pG; redC[g][k] = pC;
    __syncthreads();
    if (tid < 16) {
        float sG = 0.f, sC = 0.f;
        for (int gg = 0; gg < 16; ++gg) { sG += redG[gg][tid]; sC += redC[gg][tid]; }
        ws[WS_G + tid] = sG;
        ws[WS_C + tid] = sC + b_down[tid];
    }
    // key = memory@W_k + b_k ; val = memory@W_v + b_v
    for (int e = tid; e < MMEM*DDIM; e += 256) {
        const int m = e >> 4, kk = e & 15;
        float sk = b_k[kk], sv = b_v[kk];
        for (int dd = 0; dd < DDIM; ++dd) {
            const float mv = memory[m*DDIM + dd];
            sk = fmaf(mv, W_k[dd*DDIM + kk], sk);
            sv = fmaf(mv, W_v[dd*DDIM + kk], sv);
        }
        ws[WS_KEY + e] = sk;
        ws[WS_VAL + e] = sv;
    }
}

// accumulate one x element into stats + A[16] (weight row II, wave-uniform index)
#define ACC1(XU, II)                                                    \
    {                                                                   \
        const float xu_ = (XU);                                         \
        S0 += xu_; S1 = fmaf(xu_, xu_, S1);                             \
        const int ii_ = (II);                                           \
        _Pragma("unroll")                                               \
        for (int kq = 0; kq < 4; ++kq) {                                \
            const float4 wv = W14[ii_*4 + kq];                          \
            A[kq*4+0] = fmaf(xu_, wv.x, A[kq*4+0]);                     \
            A[kq*4+1] = fmaf(xu_, wv.y, A[kq*4+1]);                     \
            A[kq*4+2] = fmaf(xu_, wv.z, A[kq*4+2]);                     \
            A[kq*4+3] = fmaf(xu_, wv.w, A[kq*4+3]);                     \
        }                                                               \
    }

// 8 waves/block, 64 tokens/block (lane = token), H split 8 ways across waves.
// No LDS staging of x (scattered per-lane loads, every 64B line fully consumed).
__global__ __launch_bounds__(512, 4) void down_kernel(
    const float* __restrict__ x,
    const float* __restrict__ wsc,
    const float* __restrict__ g2, const float* __restrict__ b2,
    const float* __restrict__ g3, const float* __restrict__ b3,
    float* __restrict__ ws_r)
{
    __shared__ float pl[512 * 19];   // 38912 B: 18 partials/thread, stride 19 (odd)
    const int tid  = threadIdx.x;
    const int lane = tid & 63;
    const int w    = tid >> 6;       // wave id 0..7
    const int tok0 = blockIdx.x * 64;
    const int tok  = tok0 + lane;

    // this wave's H chunk: floats [w*96, w*96+96) = 24 float4 per lane
    const float4* __restrict__ x4  = (const float4*)(x + (size_t)tok * HDIM) + w * 24;
    const float4* __restrict__ W14 = (const float4*)(wsc + WS_W1);

    float A[16];
#pragma unroll
    for (int k = 0; k < 16; ++k) A[k] = 0.f;
    float S0 = 0.f, S1 = 0.f;

#pragma unroll
    for (int j = 0; j < 24; ++j) {
        const float4 v = x4[j];
        const int i0 = w * 96 + j * 4;
        ACC1(v.x, i0 + 0)
        ACC1(v.y, i0 + 1)
        ACC1(v.z, i0 + 2)
        ACC1(v.w, i0 + 3)
    }

    // write partials: base stride 19 floats -> lanes spread over all 32 banks
    const int pbase = tid * 19;
    pl[pbase + 0] = S0;
    pl[pbase + 1] = S1;
#pragma unroll
    for (int k = 0; k < 16; ++k) pl[pbase + 2 + k] = A[k];
    __syncthreads();

    if (w == 0) {
        float fS0 = S0, fS1 = S1;
        float fA[16];
#pragma unroll
        for (int k = 0; k < 16; ++k) fA[k] = A[k];
#pragma unroll
        for (int ww = 1; ww < 8; ++ww) {
            const int pb = (ww * 64 + lane) * 19;
            fS0 += pl[pb + 0];
            fS1 += pl[pb + 1];
#pragma unroll
            for (int k = 0; k < 16; ++k) fA[k] += pl[pb + 2 + k];
        }

        // LN1 (folded) -> d
        const float inv_h = 1.0f / 768.0f;
        const float mean1 = fS0 * inv_h;
        const float var1 = fmaf(-mean1, mean1, fS1 * inv_h);
        const float rs1 = rsqrtf(var1 + LN_EPS);
        float d[16];
#pragma unroll
        for (int k = 0; k < 16; ++k)
            d[k] = fmaf(rs1, fmaf(-mean1, wsc[WS_G + k], fA[k]), wsc[WS_C + k]);

        // LN2 -> q
        float t0 = 0.f;
#pragma unroll
        for (int k = 0; k < 16; ++k) t0 += d[k];
        const float mean2 = t0 * 0.0625f;
        float t1 = 0.f;
#pragma unroll
        for (int k = 0; k < 16; ++k) { const float c = d[k] - mean2; t1 = fmaf(c, c, t1); }
        const float rs2 = rsqrtf(t1 * 0.0625f + LN_EPS);
        float qv[16];
#pragma unroll
        for (int k = 0; k < 16; ++k)
            qv[k] = fmaf((d[k] - mean2) * rs2, g2[k], b2[k]);

        // two-pass softmax over 50 memories (no sc[50] storage -> no spills)
        const float* __restrict__ KEY = wsc + WS_KEY;
        const float* __restrict__ VAL = wsc + WS_VAL;
        float smax = -3.4e38f;
#pragma unroll 1
        for (int mm = 0; mm < MMEM; ++mm) {
            float a = 0.f;
#pragma unroll
            for (int k = 0; k < 16; ++k) a = fmaf(qv[k], KEY[mm*16 + k], a);
            smax = fmaxf(smax, a);
        }
        float mo[16];
#pragma unroll
        for (int k = 0; k < 16; ++k) mo[k] = 0.f;
        float ssum = 0.f;
#pragma unroll 1
        for (int mm = 0; mm < MMEM; ++mm) {
            float a = 0.f;
#pragma unroll
            for (int k = 0; k < 16; ++k) a = fmaf(qv[k], KEY[mm*16 + k], a);
            const float e = __expf(a - smax);
            ssum += e;
#pragma unroll
            for (int k = 0; k < 16; ++k) mo[k] = fmaf(e, VAL[mm*16 + k], mo[k]);
        }
        const float rn = 1.0f / ssum;
#pragma unroll
        for (int k = 0; k < 16; ++k) mo[k] *= rn;

        // LN3 -> r, store
        float u0 = 0.f;
#pragma unroll
        for (int k = 0; k < 16; ++k) u0 += mo[k];
        const float mean3 = u0 * 0.0625f;
        float u1 = 0.f;
#pragma unroll
        for (int k = 0; k < 16; ++k) { const float c = mo[k] - mean3; u1 = fmaf(c, c, u1); }
        const float rs3 = rsqrtf(u1 * 0.0625f + LN_EPS);

        float4* rw = (float4*)(ws_r + (size_t)tok * 16);
#pragma unroll
        for (int q2 = 0; q2 < 4; ++q2) {
            float4 stv;
            stv.x = fmaf((mo[q2*4+0] - mean3) * rs3, g3[q2*4+0], b3[q2*4+0]);
            stv.y = fmaf((mo[q2*4+1] - mean3) * rs3, g3[q2*4+1], b3[q2*4+1]);
            stv.z = fmaf((mo[q2*4+2] - mean3) * rs3, g3[q2*4+2], b3[q2*4+2]);
            stv.w = fmaf((mo[q2*4+3] - mean3) * rs3, g3[q2*4+3], b3[q2*4+3]);
            rw[q2] = stv;
        }
    }
}

__global__ __launch_bounds__(256) void up_kernel(
    const float* __restrict__ ws_r, const float* __restrict__ W_up,
    const float* __restrict__ b_up, float* __restrict__ out)
{
    const int lane = threadIdx.x & 63;
    const int wid = __builtin_amdgcn_readfirstlane(threadIdx.x >> 6);
    const int wg = blockIdx.x * 4 + wid;     // 0..3071
    const int jg = wg % 3;                    // 3 j-groups of 256 columns
    const int tc = wg / 3;                    // 1024 token chunks of 32
    const int j0 = jg * 256 + lane * 4;

    float4 w[16];
#pragma unroll
    for (int k = 0; k < 16; ++k)
        w[k] = *(const float4*)(W_up + k*HDIM + j0);
    const float4 bu = *(const float4*)(b_up + j0);

    const int t0 = tc * 32;
#pragma unroll 2
    for (int tt = 0; tt < 32; ++tt) {
        const int t = t0 + tt;
        const float* __restrict__ rt = ws_r + (size_t)t * 16;
        float4 acc = bu;
#pragma unroll
        for (int k = 0; k < 16; ++k) {
            const float rk = rt[k];
            acc.x = fmaf(rk, w[k].x, acc.x);
            acc.y = fmaf(rk, w[k].y, acc.y);
            acc.z = fmaf(rk, w[k].z, acc.z);
            acc.w = fmaf(rk, w[k].w, acc.w);
        }
        *(float4*)(out + (size_t)t * HDIM + j0) = acc;
    }
}

extern "C" void kernel_launch(void* const* d_in, const int* in_sizes, int n_in,
                              void* d_out, int out_size, void* d_ws, size_t ws_size,
                              hipStream_t stream) {
    const float* x      = (const float*)d_in[0];
    const float* g1     = (const float*)d_in[1];
    const float* b1     = (const float*)d_in[2];
    const float* W_down = (const float*)d_in[3];
    const float* b_down = (const float*)d_in[4];
    const float* g2     = (const float*)d_in[5];
    const float* b2     = (const float*)d_in[6];
    const float* memory = (const float*)d_in[7];
    const float* W_k    = (const float*)d_in[8];
    const float* b_k    = (const float*)d_in[9];
    const float* W_v    = (const float*)d_in[10];
    const float* b_v    = (const float*)d_in[11];
    const float* g3     = (const float*)d_in[12];
    const float* b3     = (const float*)d_in[13];
    const float* W_up   = (const float*)d_in[14];
    const float* b_up   = (const float*)d_in[15];
    float* out = (float*)d_out;
    float* ws  = (float*)d_ws;

    hipLaunchKernelGGL(pre_kernel, dim3(1), dim3(256), 0, stream,
                       g1, b1, W_down, b_down, memory, W_k, b_k, W_v, b_v, ws);
    hipLaunchKernelGGL(down_kernel, dim3(NTOK/64), dim3(512), 0, stream,
                       x, ws, g2, b2, g3, b3, ws + WS_R);
    hipLaunchKernelGGL(up_kernel, dim3(768), dim3(256), 0, stream,
                       ws + WS_R, W_up, b_up, out);
}

// Round 4
// 118.815 us; speedup vs baseline: 1.9592x; 1.9592x over previous
//
#include <hip/hip_runtime.h>
#include <cstdint>

#define LN_EPS 1e-12f
#define NTOK 32768
#define HDIM 768
#define DDIM 16
#define MMEM 50

// ws layout (floats)
#define WS_W1   0        // 12288: g1-folded W_down
#define WS_G    12288    // 16
#define WS_C    12304    // 16 (includes b_down)
#define WS_KEY  12320    // 800
#define WS_VAL  13120    // 800
#define WS_R    16384    // 32768*16

__global__ __launch_bounds__(256) void pre_kernel(
    const float* __restrict__ g1, const float* __restrict__ b1,
    const float* __restrict__ W_down, const float* __restrict__ b_down,
    const float* __restrict__ memory, const float* __restrict__ W_k,
    const float* __restrict__ b_k, const float* __restrict__ W_v,
    const float* __restrict__ b_v, float* __restrict__ ws)
{
    const int tid = threadIdx.x;
    // W1 = diag(g1) @ W_down
    const float4* Wd4 = (const float4*)W_down;
    float4* W14 = (float4*)(ws + WS_W1);
    for (int e = tid; e < (HDIM*DDIM)/4; e += 256) {
        const int i = e >> 2;
        float4 w = Wd4[e];
        const float s = g1[i];
        w.x *= s; w.y *= s; w.z *= s; w.w *= s;
        W14[e] = w;
    }
    // G[k] = sum_i g1[i]*Wd[i,k];  C[k] = sum_i b1[i]*Wd[i,k] + b_down[k]
    __shared__ float redG[16][17];
    __shared__ float redC[16][17];
    const int k = tid & 15, g = tid >> 4;
    float pG = 0.f, pC = 0.f;
    for (int i = g*(HDIM/16); i < (g+1)*(HDIM/16); ++i) {
        const float w = W_down[i*DDIM + k];
        pG = fmaf(g1[i], w, pG);
        pC = fmaf(b1[i], w, pC);
    }
    redG[g][k] = pG; redC[g][k] = pC;
    __syncthreads();
    if (tid < 16) {
        float sG = 0.f, sC = 0.f;
        for (int gg = 0; gg < 16; ++gg) { sG += redG[gg][tid]; sC += redC[gg][tid]; }
        ws[WS_G + tid] = sG;
        ws[WS_C + tid] = sC + b_down[tid];
    }
    // key = memory@W_k + b_k ; val = memory@W_v + b_v
    for (int e = tid; e < MMEM*DDIM; e += 256) {
        const int m = e >> 4, kk = e & 15;
        float sk = b_k[kk], sv = b_v[kk];
        for (int dd = 0; dd < DDIM; ++dd) {
            const float mv = memory[m*DDIM + dd];
            sk = fmaf(mv, W_k[dd*DDIM + kk], sk);
            sv = fmaf(mv, W_v[dd*DDIM + kk], sv);
        }
        ws[WS_KEY + e] = sk;
        ws[WS_VAL + e] = sv;
    }
}

// accumulate one x element into stats + A[16]; II must be WAVE-UNIFORM so the
// four W14 float4 loads select to s_load (scalar pipe), not vector loads.
#define ACC1(XU, II)                                                    \
    {                                                                   \
        const float xu_ = (XU);                                         \
        S0 += xu_; S1 = fmaf(xu_, xu_, S1);                             \
        const int ii_ = (II);                                           \
        _Pragma("unroll")                                               \
        for (int kq = 0; kq < 4; ++kq) {                                \
            const float4 wv = W14[ii_*4 + kq];                          \
            A[kq*4+0] = fmaf(xu_, wv.x, A[kq*4+0]);                     \
            A[kq*4+1] = fmaf(xu_, wv.y, A[kq*4+1]);                     \
            A[kq*4+2] = fmaf(xu_, wv.z, A[kq*4+2]);                     \
            A[kq*4+3] = fmaf(xu_, wv.w, A[kq*4+3]);                     \
        }                                                               \
    }

// 8 waves/block, 64 tokens/block (lane = token), H split 8 ways across waves.
// w is readfirstlane'd -> weight indices wave-uniform -> scalar weight loads.
__global__ __launch_bounds__(512, 4) void down_kernel(
    const float* __restrict__ x,
    const float* __restrict__ wsc,
    const float* __restrict__ g2, const float* __restrict__ b2,
    const float* __restrict__ g3, const float* __restrict__ b3,
    float* __restrict__ ws_r)
{
    __shared__ float pl[512 * 19];   // 38912 B: 18 partials/thread, stride 19 (odd)
    const int tid  = threadIdx.x;
    const int lane = tid & 63;
    const int w    = __builtin_amdgcn_readfirstlane(tid >> 6);  // wave id 0..7, SGPR
    const int tok0 = blockIdx.x * 64;
    const int tok  = tok0 + lane;

    // this wave's H chunk: floats [w*96, w*96+96) = 24 float4 per lane
    const float4* __restrict__ x4  = (const float4*)(x + (size_t)tok * HDIM) + w * 24;
    const float4* __restrict__ W14 = (const float4*)(wsc + WS_W1);

    float A[16];
#pragma unroll
    for (int k = 0; k < 16; ++k) A[k] = 0.f;
    float S0 = 0.f, S1 = 0.f;

#pragma unroll
    for (int j = 0; j < 24; ++j) {
        const float4 v = x4[j];
        const int i0 = w * 96 + j * 4;   // uniform (w is SGPR, j is constant)
        ACC1(v.x, i0 + 0)
        ACC1(v.y, i0 + 1)
        ACC1(v.z, i0 + 2)
        ACC1(v.w, i0 + 3)
    }

    // write partials: stride 19 floats (odd) -> spread over all 32 banks
    const int pbase = tid * 19;
    pl[pbase + 0] = S0;
    pl[pbase + 1] = S1;
#pragma unroll
    for (int k = 0; k < 16; ++k) pl[pbase + 2 + k] = A[k];
    __syncthreads();

    if (w == 0) {   // scalar branch: waves 1..7 exit
        float fS0 = S0, fS1 = S1;
        float fA[16];
#pragma unroll
        for (int k = 0; k < 16; ++k) fA[k] = A[k];
#pragma unroll
        for (int ww = 1; ww < 8; ++ww) {
            const int pb = (ww * 64 + lane) * 19;
            fS0 += pl[pb + 0];
            fS1 += pl[pb + 1];
#pragma unroll
            for (int k = 0; k < 16; ++k) fA[k] += pl[pb + 2 + k];
        }

        // LN1 (folded) -> d
        const float inv_h = 1.0f / 768.0f;
        const float mean1 = fS0 * inv_h;
        const float var1 = fmaf(-mean1, mean1, fS1 * inv_h);
        const float rs1 = rsqrtf(var1 + LN_EPS);
        float d[16];
#pragma unroll
        for (int k = 0; k < 16; ++k)
            d[k] = fmaf(rs1, fmaf(-mean1, wsc[WS_G + k], fA[k]), wsc[WS_C + k]);

        // LN2 -> q
        float t0 = 0.f;
#pragma unroll
        for (int k = 0; k < 16; ++k) t0 += d[k];
        const float mean2 = t0 * 0.0625f;
        float t1 = 0.f;
#pragma unroll
        for (int k = 0; k < 16; ++k) { const float c = d[k] - mean2; t1 = fmaf(c, c, t1); }
        const float rs2 = rsqrtf(t1 * 0.0625f + LN_EPS);
        float qv[16];
#pragma unroll
        for (int k = 0; k < 16; ++k)
            qv[k] = fmaf((d[k] - mean2) * rs2, g2[k], b2[k]);

        // two-pass softmax over 50 memories (no sc[50] storage)
        const float* __restrict__ KEY = wsc + WS_KEY;
        const float* __restrict__ VAL = wsc + WS_VAL;
        float smax = -3.4e38f;
#pragma unroll 1
        for (int mm = 0; mm < MMEM; ++mm) {
            float a = 0.f;
#pragma unroll
            for (int k = 0; k < 16; ++k) a = fmaf(qv[k], KEY[mm*16 + k], a);
            smax = fmaxf(smax, a);
        }
        float mo[16];
#pragma unroll
        for (int k = 0; k < 16; ++k) mo[k] = 0.f;
        float ssum = 0.f;
#pragma unroll 1
        for (int mm = 0; mm < MMEM; ++mm) {
            float a = 0.f;
#pragma unroll
            for (int k = 0; k < 16; ++k) a = fmaf(qv[k], KEY[mm*16 + k], a);
            const float e = __expf(a - smax);
            ssum += e;
#pragma unroll
            for (int k = 0; k < 16; ++k) mo[k] = fmaf(e, VAL[mm*16 + k], mo[k]);
        }
        const float rn = 1.0f / ssum;
#pragma unroll
        for (int k = 0; k < 16; ++k) mo[k] *= rn;

        // LN3 -> r, store
        float u0 = 0.f;
#pragma unroll
        for (int k = 0; k < 16; ++k) u0 += mo[k];
        const float mean3 = u0 * 0.0625f;
        float u1 = 0.f;
#pragma unroll
        for (int k = 0; k < 16; ++k) { const float c = mo[k] - mean3; u1 = fmaf(c, c, u1); }
        const float rs3 = rsqrtf(u1 * 0.0625f + LN_EPS);

        float4* rw = (float4*)(ws_r + (size_t)tok * 16);
#pragma unroll
        for (int q2 = 0; q2 < 4; ++q2) {
            float4 stv;
            stv.x = fmaf((mo[q2*4+0] - mean3) * rs3, g3[q2*4+0], b3[q2*4+0]);
            stv.y = fmaf((mo[q2*4+1] - mean3) * rs3, g3[q2*4+1], b3[q2*4+1]);
            stv.z = fmaf((mo[q2*4+2] - mean3) * rs3, g3[q2*4+2], b3[q2*4+2]);
            stv.w = fmaf((mo[q2*4+3] - mean3) * rs3, g3[q2*4+3], b3[q2*4+3]);
            rw[q2] = stv;
        }
    }
}

__global__ __launch_bounds__(256) void up_kernel(
    const float* __restrict__ ws_r, const float* __restrict__ W_up,
    const float* __restrict__ b_up, float* __restrict__ out)
{
    const int lane = threadIdx.x & 63;
    const int wid = __builtin_amdgcn_readfirstlane(threadIdx.x >> 6);
    const int wg = blockIdx.x * 4 + wid;     // 0..3071
    const int jg = wg % 3;                    // 3 j-groups of 256 columns
    const int tc = wg / 3;                    // 1024 token chunks of 32
    const int j0 = jg * 256 + lane * 4;

    float4 w[16];
#pragma unroll
    for (int k = 0; k < 16; ++k)
        w[k] = *(const float4*)(W_up + k*HDIM + j0);
    const float4 bu = *(const float4*)(b_up + j0);

    const int t0 = tc * 32;
#pragma unroll 2
    for (int tt = 0; tt < 32; ++tt) {
        const int t = t0 + tt;
        const float* __restrict__ rt = ws_r + (size_t)t * 16;
        float4 acc = bu;
#pragma unroll
        for (int k = 0; k < 16; ++k) {
            const float rk = rt[k];
            acc.x = fmaf(rk, w[k].x, acc.x);
            acc.y = fmaf(rk, w[k].y, acc.y);
            acc.z = fmaf(rk, w[k].z, acc.z);
            acc.w = fmaf(rk, w[k].w, acc.w);
        }
        *(float4*)(out + (size_t)t * HDIM + j0) = acc;
    }
}

extern "C" void kernel_launch(void* const* d_in, const int* in_sizes, int n_in,
                              void* d_out, int out_size, void* d_ws, size_t ws_size,
                              hipStream_t stream) {
    const float* x      = (const float*)d_in[0];
    const float* g1     = (const float*)d_in[1];
    const float* b1     = (const float*)d_in[2];
    const float* W_down = (const float*)d_in[3];
    const float* b_down = (const float*)d_in[4];
    const float* g2     = (const float*)d_in[5];
    const float* b2     = (const float*)d_in[6];
    const float* memory = (const float*)d_in[7];
    const float* W_k    = (const float*)d_in[8];
    const float* b_k    = (const float*)d_in[9];
    const float* W_v    = (const float*)d_in[10];
    const float* b_v    = (const float*)d_in[11];
    const float* g3     = (const float*)d_in[12];
    const float* b3     = (const float*)d_in[13];
    const float* W_up   = (const float*)d_in[14];
    const float* b_up   = (const float*)d_in[15];
    float* out = (float*)d_out;
    float* ws  = (float*)d_ws;

    hipLaunchKernelGGL(pre_kernel, dim3(1), dim3(256), 0, stream,
                       g1, b1, W_down, b_down, memory, W_k, b_k, W_v, b_v, ws);
    hipLaunchKernelGGL(down_kernel, dim3(NTOK/64), dim3(512), 0, stream,
                       x, ws, g2, b2, g3, b3, ws + WS_R);
    hipLaunchKernelGGL(up_kernel, dim3(768), dim3(256), 0, stream,
                       ws + WS_R, W_up, b_up, out);
}

// Round 5
// 113.632 us; speedup vs baseline: 2.0486x; 1.0456x over previous
//
#include <hip/hip_runtime.h>
#include <cstdint>

#define LN_EPS 1e-12f
#define NTOK 32768
#define HDIM 768
#define DDIM 16
#define MMEM 50

// ws layout (floats)
#define WS_W1   0        // 12288: g1-folded W_down
#define WS_G    12288    // 16
#define WS_C    12304    // 16 (includes b_down)
#define WS_KEY  12320    // 800
#define WS_VAL  13120    // 800
#define WS_R    16384    // 32768*16

__global__ __launch_bounds__(256) void pre_kernel(
    const float* __restrict__ g1, const float* __restrict__ b1,
    const float* __restrict__ W_down, const float* __restrict__ b_down,
    const float* __restrict__ memory, const float* __restrict__ W_k,
    const float* __restrict__ b_k, const float* __restrict__ W_v,
    const float* __restrict__ b_v, float* __restrict__ ws)
{
    const int tid = threadIdx.x;
    // W1 = diag(g1) @ W_down
    const float4* Wd4 = (const float4*)W_down;
    float4* W14 = (float4*)(ws + WS_W1);
    for (int e = tid; e < (HDIM*DDIM)/4; e += 256) {
        const int i = e >> 2;
        float4 w = Wd4[e];
        const float s = g1[i];
        w.x *= s; w.y *= s; w.z *= s; w.w *= s;
        W14[e] = w;
    }
    // G[k] = sum_i g1[i]*Wd[i,k];  C[k] = sum_i b1[i]*Wd[i,k] + b_down[k]
    __shared__ float redG[16][17];
    __shared__ float redC[16][17];
    const int k = tid & 15, g = tid >> 4;
    float pG = 0.f, pC = 0.f;
    for (int i = g*(HDIM/16); i < (g+1)*(HDIM/16); ++i) {
        const float w = W_down[i*DDIM + k];
        pG = fmaf(g1[i], w, pG);
        pC = fmaf(b1[i], w, pC);
    }
    redG[g][k] = pG; redC[g][k] = pC;
    __syncthreads();
    if (tid < 16) {
        float sG = 0.f, sC = 0.f;
        for (int gg = 0; gg < 16; ++gg) { sG += redG[gg][tid]; sC += redC[gg][tid]; }
        ws[WS_G + tid] = sG;
        ws[WS_C + tid] = sC + b_down[tid];
    }
    // key = memory@W_k + b_k ; val = memory@W_v + b_v
    for (int e = tid; e < MMEM*DDIM; e += 256) {
        const int m = e >> 4, kk = e & 15;
        float sk = b_k[kk], sv = b_v[kk];
        for (int dd = 0; dd < DDIM; ++dd) {
            const float mv = memory[m*DDIM + dd];
            sk = fmaf(mv, W_k[dd*DDIM + kk], sk);
            sv = fmaf(mv, W_v[dd*DDIM + kk], sv);
        }
        ws[WS_KEY + e] = sk;
        ws[WS_VAL + e] = sv;
    }
}

// accumulate one x element into stats + A[16]; II must be WAVE-UNIFORM so the
// four W14 float4 loads select to s_load (scalar pipe), not vector loads.
#define ACC1(XU, II)                                                    \
    {                                                                   \
        const float xu_ = (XU);                                         \
        S0 += xu_; S1 = fmaf(xu_, xu_, S1);                             \
        const int ii_ = (II);                                           \
        _Pragma("unroll")                                               \
        for (int kq = 0; kq < 4; ++kq) {                                \
            const float4 wv = W14[ii_*4 + kq];                          \
            A[kq*4+0] = fmaf(xu_, wv.x, A[kq*4+0]);                     \
            A[kq*4+1] = fmaf(xu_, wv.y, A[kq*4+1]);                     \
            A[kq*4+2] = fmaf(xu_, wv.z, A[kq*4+2]);                     \
            A[kq*4+3] = fmaf(xu_, wv.w, A[kq*4+3]);                     \
        }                                                               \
    }

// Stage H-chunk KK (128 floats) of this block's 64 tokens into buffer B.
// Tile layout: slot S = row*32 + c', 16B slots, LINEAR in LDS (gload_lds writes
// base+lane*16). Swizzle via SOURCE: slot (row,c') holds x[row][h0 + 4*(c'^(row&7))].
// Wave w covers S in [w*256, w*256+256) -> 4 instrs of 64 slots (2 rows each).
#define STAGE(KK, B)                                                            \
    {                                                                           \
        _Pragma("unroll")                                                       \
        for (int i_ = 0; i_ < 4; ++i_) {                                        \
            const int S_   = w*256 + i_*64 + lane;                              \
            const int row_ = S_ >> 5;                                           \
            const int c_   = (S_ & 31) ^ (row_ & 7);                            \
            const float* src_ = x + (size_t)(tok0 + row_) * HDIM                \
                                  + (KK)*128 + (c_ << 2);                       \
            float* dst_ = smem + (B)*8192 + (w*256 + i_*64)*4;                  \
            __builtin_amdgcn_global_load_lds(                                   \
                (const __attribute__((address_space(1))) unsigned int*)src_,    \
                (__attribute__((address_space(3))) unsigned int*)dst_,          \
                16, 0, 0);                                                      \
        }                                                                       \
    }

// Compute chunk KK from buffer B: lane = token, wave w handles slots 4w..4w+3.
#define COMPUTE(KK, B)                                                          \
    {                                                                           \
        _Pragma("unroll")                                                       \
        for (int j_ = 0; j_ < 4; ++j_) {                                        \
            const int c_  = w*4 + j_;              /* uniform */                \
            const int sw_ = c_ ^ (lane & 7);       /* per-lane swizzled col */  \
            const float4 v_ = *(const float4*)(smem + (B)*8192                  \
                                               + (lane*32 + sw_)*4);            \
            const int i0_ = (KK)*128 + c_*4;       /* uniform weight row */     \
            ACC1(v_.x, i0_ + 0)                                                 \
            ACC1(v_.y, i0_ + 1)                                                 \
            ACC1(v_.z, i0_ + 2)                                                 \
            ACC1(v_.w, i0_ + 3)                                                 \
        }                                                                       \
    }

// 8 waves/block, 64 tokens/block (lane = token). x staged coalesced via
// global_load_lds into a double-buffered swizzled LDS tile; LDS does the scatter.
__global__ __launch_bounds__(512, 4) void down_kernel(
    const float* __restrict__ x,
    const float* __restrict__ wsc,
    const float* __restrict__ g2, const float* __restrict__ b2,
    const float* __restrict__ g3, const float* __restrict__ b3,
    float* __restrict__ ws_r)
{
    __shared__ float smem[16384];    // 64 KB: 2 x 32KB tile buffers; reused as pl after
    const int tid  = threadIdx.x;
    const int lane = tid & 63;
    const int w    = __builtin_amdgcn_readfirstlane(tid >> 6);  // wave id 0..7, SGPR
    const int tok0 = blockIdx.x * 64;
    const int tok  = tok0 + lane;

    const float4* __restrict__ W14 = (const float4*)(wsc + WS_W1);

    float A[16];
#pragma unroll
    for (int k = 0; k < 16; ++k) A[k] = 0.f;
    float S0 = 0.f, S1 = 0.f;

    STAGE(0, 0)
    asm volatile("s_waitcnt vmcnt(0)");
    __syncthreads();

#pragma unroll
    for (int kc = 0; kc < 6; ++kc) {
        const int p = kc & 1;
        if (kc < 5) STAGE(kc + 1, p ^ 1)     // prefetch next chunk into other buffer
        COMPUTE(kc, p)                        // overlap compute with in-flight loads
        asm volatile("s_waitcnt vmcnt(0)");
        __syncthreads();
    }

    // cross-wave partial reduction; pl aliases smem (tile reads all done, behind barrier)
    float* pl = smem;
    const int pbase = tid * 19;
    pl[pbase + 0] = S0;
    pl[pbase + 1] = S1;
#pragma unroll
    for (int k = 0; k < 16; ++k) pl[pbase + 2 + k] = A[k];
    __syncthreads();

    if (w == 0) {   // waves 1..7 exit
        float fS0 = S0, fS1 = S1;
        float fA[16];
#pragma unroll
        for (int k = 0; k < 16; ++k) fA[k] = A[k];
#pragma unroll
        for (int ww = 1; ww < 8; ++ww) {
            const int pb = (ww * 64 + lane) * 19;
            fS0 += pl[pb + 0];
            fS1 += pl[pb + 1];
#pragma unroll
            for (int k = 0; k < 16; ++k) fA[k] += pl[pb + 2 + k];
        }

        // LN1 (folded) -> d
        const float inv_h = 1.0f / 768.0f;
        const float mean1 = fS0 * inv_h;
        const float var1 = fmaf(-mean1, mean1, fS1 * inv_h);
        const float rs1 = rsqrtf(var1 + LN_EPS);
        float d[16];
#pragma unroll
        for (int k = 0; k < 16; ++k)
            d[k] = fmaf(rs1, fmaf(-mean1, wsc[WS_G + k], fA[k]), wsc[WS_C + k]);

        // LN2 -> q
        float t0 = 0.f;
#pragma unroll
        for (int k = 0; k < 16; ++k) t0 += d[k];
        const float mean2 = t0 * 0.0625f;
        float t1 = 0.f;
#pragma unroll
        for (int k = 0; k < 16; ++k) { const float c = d[k] - mean2; t1 = fmaf(c, c, t1); }
        const float rs2 = rsqrtf(t1 * 0.0625f + LN_EPS);
        float qv[16];
#pragma unroll
        for (int k = 0; k < 16; ++k)
            qv[k] = fmaf((d[k] - mean2) * rs2, g2[k], b2[k]);

        // two-pass softmax over 50 memories (no sc[50] storage)
        const float* __restrict__ KEY = wsc + WS_KEY;
        const float* __restrict__ VAL = wsc + WS_VAL;
        float smax = -3.4e38f;
#pragma unroll 1
        for (int mm = 0; mm < MMEM; ++mm) {
            float a = 0.f;
#pragma unroll
            for (int k = 0; k < 16; ++k) a = fmaf(qv[k], KEY[mm*16 + k], a);
            smax = fmaxf(smax, a);
        }
        float mo[16];
#pragma unroll
        for (int k = 0; k < 16; ++k) mo[k] = 0.f;
        float ssum = 0.f;
#pragma unroll 1
        for (int mm = 0; mm < MMEM; ++mm) {
            float a = 0.f;
#pragma unroll
            for (int k = 0; k < 16; ++k) a = fmaf(qv[k], KEY[mm*16 + k], a);
            const float e = __expf(a - smax);
            ssum += e;
#pragma unroll
            for (int k = 0; k < 16; ++k) mo[k] = fmaf(e, VAL[mm*16 + k], mo[k]);
        }
        const float rn = 1.0f / ssum;
#pragma unroll
        for (int k = 0; k < 16; ++k) mo[k] *= rn;

        // LN3 -> r, store
        float u0 = 0.f;
#pragma unroll
        for (int k = 0; k < 16; ++k) u0 += mo[k];
        const float mean3 = u0 * 0.0625f;
        float u1 = 0.f;
#pragma unroll
        for (int k = 0; k < 16; ++k) { const float c = mo[k] - mean3; u1 = fmaf(c, c, u1); }
        const float rs3 = rsqrtf(u1 * 0.0625f + LN_EPS);

        float4* rw = (float4*)(ws_r + (size_t)tok * 16);
#pragma unroll
        for (int q2 = 0; q2 < 4; ++q2) {
            float4 stv;
            stv.x = fmaf((mo[q2*4+0] - mean3) * rs3, g3[q2*4+0], b3[q2*4+0]);
            stv.y = fmaf((mo[q2*4+1] - mean3) * rs3, g3[q2*4+1], b3[q2*4+1]);
            stv.z = fmaf((mo[q2*4+2] - mean3) * rs3, g3[q2*4+2], b3[q2*4+2]);
            stv.w = fmaf((mo[q2*4+3] - mean3) * rs3, g3[q2*4+3], b3[q2*4+3]);
            rw[q2] = stv;
        }
    }
}

__global__ __launch_bounds__(256) void up_kernel(
    const float* __restrict__ ws_r, const float* __restrict__ W_up,
    const float* __restrict__ b_up, float* __restrict__ out)
{
    const int lane = threadIdx.x & 63;
    const int wid = __builtin_amdgcn_readfirstlane(threadIdx.x >> 6);
    const int wg = blockIdx.x * 4 + wid;     // 0..3071
    const int jg = wg % 3;                    // 3 j-groups of 256 columns
    const int tc = wg / 3;                    // 1024 token chunks of 32
    const int j0 = jg * 256 + lane * 4;

    float4 w[16];
#pragma unroll
    for (int k = 0; k < 16; ++k)
        w[k] = *(const float4*)(W_up + k*HDIM + j0);
    const float4 bu = *(const float4*)(b_up + j0);

    const int t0 = tc * 32;
#pragma unroll 2
    for (int tt = 0; tt < 32; ++tt) {
        const int t = t0 + tt;
        const float* __restrict__ rt = ws_r + (size_t)t * 16;
        float4 acc = bu;
#pragma unroll
        for (int k = 0; k < 16; ++k) {
            const float rk = rt[k];
            acc.x = fmaf(rk, w[k].x, acc.x);
            acc.y = fmaf(rk, w[k].y, acc.y);
            acc.z = fmaf(rk, w[k].z, acc.z);
            acc.w = fmaf(rk, w[k].w, acc.w);
        }
        *(float4*)(out + (size_t)t * HDIM + j0) = acc;
    }
}

extern "C" void kernel_launch(void* const* d_in, const int* in_sizes, int n_in,
                              void* d_out, int out_size, void* d_ws, size_t ws_size,
                              hipStream_t stream) {
    const float* x      = (const float*)d_in[0];
    const float* g1     = (const float*)d_in[1];
    const float* b1     = (const float*)d_in[2];
    const float* W_down = (const float*)d_in[3];
    const float* b_down = (const float*)d_in[4];
    const float* g2     = (const float*)d_in[5];
    const float* b2     = (const float*)d_in[6];
    const float* memory = (const float*)d_in[7];
    const float* W_k    = (const float*)d_in[8];
    const float* b_k    = (const float*)d_in[9];
    const float* W_v    = (const float*)d_in[10];
    const float* b_v    = (const float*)d_in[11];
    const float* g3     = (const float*)d_in[12];
    const float* b3     = (const float*)d_in[13];
    const float* W_up   = (const float*)d_in[14];
    const float* b_up   = (const float*)d_in[15];
    float* out = (float*)d_out;
    float* ws  = (float*)d_ws;

    hipLaunchKernelGGL(pre_kernel, dim3(1), dim3(256), 0, stream,
                       g1, b1, W_down, b_down, memory, W_k, b_k, W_v, b_v, ws);
    hipLaunchKernelGGL(down_kernel, dim3(NTOK/64), dim3(512), 0, stream,
                       x, ws, g2, b2, g3, b3, ws + WS_R);
    hipLaunchKernelGGL(up_kernel, dim3(768), dim3(256), 0, stream,
                       ws + WS_R, W_up, b_up, out);
}